// Round 3
// baseline (574.671 us; speedup 1.0000x reference)
//
#include <hip/hip_runtime.h>
#include <stdint.h>

#define T_TOK 4096
#define D_DIM 1024
#define F_DIM 4096
#define NEXP 8
#define BMX 256        // tile M = N = 256
#define BKX 64         // K-step
#define CAP 10240      // 8192 pairs + 8*255 worst-case padding, 256-aligned
#define MT_MAX (CAP / BMX)
#define HT 16384       // half-tile bytes (256 rows x 32 k x bf16)

typedef __attribute__((ext_vector_type(8))) short short8;
typedef __attribute__((ext_vector_type(4))) float f4;
typedef __attribute__((ext_vector_type(4))) unsigned short us4;

// ---- ws layout (bytes) ----
#define WS_CNT     0
#define WS_CUR     32
#define WS_SBASE   64
#define WS_TBASE   96
#define WS_TOPI    256
#define WS_TOPP    (WS_TOPI + T_TOK*2*4)
#define WS_PSLOT   (WS_TOPP + T_TOK*2*4)
#define WS_XG      102400                               // bf16 [CAP][D]; later reused as Y
#define WS_H       (WS_XG + (size_t)CAP*D_DIM*2)        // bf16 [CAP][F]
#define WS_WT      (WS_H + (size_t)CAP*F_DIM*2)         // bf16 [E][N][K] (67 MB, reused)
#define WT_BYTES   ((size_t)NEXP*D_DIM*F_DIM*2)

__device__ __forceinline__ unsigned short f2bf(float f) {
    union { float f; uint32_t u; } c; c.f = f;
    uint32_t r = c.u + 0x7FFFu + ((c.u >> 16) & 1u);
    return (unsigned short)(r >> 16);
}
__device__ __forceinline__ float bf2f(unsigned short h) {
    union { uint32_t u; float f; } c; c.u = ((uint32_t)h) << 16;
    return c.f;
}

// ---------------- gate: fp32 logits, top-2, softmax ----------------
__global__ __launch_bounds__(256) void gate_kernel(
    const float* __restrict__ x, const float* __restrict__ gw,
    const float* __restrict__ gb,
    int* __restrict__ top_idx, float* __restrict__ top_p, int* __restrict__ cnt)
{
    int lane = threadIdx.x & 63;
    int t = blockIdx.x * 4 + (threadIdx.x >> 6);
    const float* xr = x + (size_t)t * D_DIM;
    float acc[8] = {0.f,0.f,0.f,0.f,0.f,0.f,0.f,0.f};
    for (int i = 0; i < 16; ++i) {
        int d = lane + i * 64;
        float xv = xr[d];
        const float* g = gw + d * 8;
        #pragma unroll
        for (int e = 0; e < 8; ++e) acc[e] += xv * g[e];
    }
    #pragma unroll
    for (int e = 0; e < 8; ++e) {
        #pragma unroll
        for (int off = 32; off > 0; off >>= 1)
            acc[e] += __shfl_xor(acc[e], off, 64);
    }
    if (lane == 0) {
        float l[8];
        #pragma unroll
        for (int e = 0; e < 8; ++e) l[e] = acc[e] + gb[e];
        int i0 = 0; float m0 = l[0];
        #pragma unroll
        for (int e = 1; e < 8; ++e) if (l[e] > m0) { m0 = l[e]; i0 = e; }
        int i1 = -1; float m1 = -3.4e38f;
        #pragma unroll
        for (int e = 0; e < 8; ++e) if (e != i0 && l[e] > m1) { m1 = l[e]; i1 = e; }
        float p0 = 1.f / (1.f + expf(m1 - m0));
        top_idx[t*2]   = i0; top_idx[t*2+1] = i1;
        top_p[t*2]     = p0; top_p[t*2+1]   = 1.f - p0;
        atomicAdd(&cnt[i0], 1);
        atomicAdd(&cnt[i1], 1);
    }
}

// ---------------- bases: pad counts to BMX=256, prefix sums ----------------
__global__ void bases_kernel(const int* __restrict__ cnt,
                             int* __restrict__ sbase, int* __restrict__ tbase)
{
    if (threadIdx.x == 0) {
        int b = 0, tb = 0;
        tbase[0] = 0;
        for (int e = 0; e < 8; ++e) {
            sbase[e] = b;
            int mt = (cnt[e] + BMX - 1) / BMX;
            b  += mt * BMX;
            tb += mt;
            tbase[e + 1] = tb;
        }
    }
}

// ---------------- gather ----------------
__global__ __launch_bounds__(256) void gather_kernel(
    const float* __restrict__ x, const int* __restrict__ top_idx,
    int* __restrict__ cursor, const int* __restrict__ sbase,
    int* __restrict__ pair_slot, uint16_t* __restrict__ xg)
{
    __shared__ int s_slot;
    int p = blockIdx.x;
    int t = p >> 1;
    if (threadIdx.x == 0) {
        int e = top_idx[p];
        int slot = sbase[e] + atomicAdd(&cursor[e], 1);
        pair_slot[p] = slot;
        s_slot = slot;
    }
    __syncthreads();
    int slot = s_slot;
    const f4* src = (const f4*)(x + (size_t)t * D_DIM);
    uint16_t* dst = xg + (size_t)slot * D_DIM;
    int i = threadIdx.x;
    f4 v = src[i];
    us4 o;
    o.x = f2bf(v[0]); o.y = f2bf(v[1]); o.z = f2bf(v[2]); o.w = f2bf(v[3]);
    *(us4*)(dst + i * 4) = o;
}

// ---------------- weight convert+transpose: fp32 [E][K][N] -> bf16 [E][N][K] ----------------
__global__ __launch_bounds__(256) void convT_kernel(
    const float* __restrict__ W, uint16_t* __restrict__ WT, int K, int N)
{
    __shared__ float t[32][33];
    int e = blockIdx.z;
    int n0 = blockIdx.x * 32, k0 = blockIdx.y * 32;
    const float* src = W + (size_t)e * K * N + (size_t)k0 * N + n0;
    int r = threadIdx.x >> 3, cq = threadIdx.x & 7;
    f4 v = *(const f4*)(src + (size_t)r * N + cq * 4);
    t[r][cq*4+0] = v[0]; t[r][cq*4+1] = v[1];
    t[r][cq*4+2] = v[2]; t[r][cq*4+3] = v[3];
    __syncthreads();
    us4 o;
    o.x = f2bf(t[cq*4+0][r]); o.y = f2bf(t[cq*4+1][r]);
    o.z = f2bf(t[cq*4+2][r]); o.w = f2bf(t[cq*4+3][r]);
    *(us4*)(WT + (size_t)e * N * K + (size_t)(n0 + r) * K + k0 + cq * 4) = o;
}

// ---------------- grouped GEMM, 256x256 tile, 8-phase schedule ----------------
// A [CAP][K] bf16, Bt [E][N][K] bf16 -> C [CAP][N] bf16 (+bias, opt ReLU).
// 512 thr = 8 waves (2M x 4N), per-wave 128x64 out, acc[8][4] of f32x4.
// LDS = ring of 8 half-tile regions (16 KB): K-tile t gives half-tiles
// h=4t+{Ak0,Bk0,Ak1,Bk1}, region h&7. Stage lead = 4 phases (1 half-tile/phase,
// 2x global_load_lds w16, XOR-pre-swizzled global source; reads use same XOR).
// Counted vmcnt(4) at odd phases (vmcnt(0) only at final drain). Raw barriers,
// lgkmcnt(0)+sched_barrier(0) before MFMA cluster wrapped in setprio(1/0).
template<bool RELU>
__global__ __launch_bounds__(512, 2) void moe_gemm8(
    const uint16_t* __restrict__ A, const uint16_t* __restrict__ Bt,
    const float* __restrict__ bias, uint16_t* __restrict__ Cc,
    const int* __restrict__ tbase, const int* __restrict__ sbase,
    int K, int N, int NT)
{
    __shared__ uint16_t lds[8 * HT / 2];   // 128 KB

    // XCD swizzle (nwg multiple of 8) + chunk-of-4 m-tiles for L2 locality
    int nwg = gridDim.x;
    int lin = blockIdx.x;
    int wg = (lin & 7) * (nwg >> 3) + (lin >> 3);
    int q = wg >> 2;
    int nt = q % NT;
    int mt = (wg & 3) + (q / NT) * 4;

    if (mt >= tbase[8]) return;
    int e = 0;
    while (mt >= tbase[e + 1]) ++e;
    int row0 = sbase[e] + (mt - tbase[e]) * BMX;
    int n0 = nt * BMX;
    const uint16_t* Be = Bt + (size_t)e * N * K + (size_t)n0 * K;

    int tid = threadIdx.x;
    int wid = tid >> 6, lane = tid & 63;
    int wr = wid >> 2, wc = wid & 3;
    int lq = lane >> 4, lr = lane & 15;

    // fragment read offsets within a 16 KB half-tile region ([256 rows][32 k],
    // 16B k-block XOR-swizzled by s(row) = (row + row/4) & 3 -> worst 2-way)
    int aoff[8], boff[4];
    #pragma unroll
    for (int m = 0; m < 8; ++m) {
        int r = wr * 128 + m * 16 + lr;
        int s = (r + (r >> 2)) & 3;
        aoff[m] = r * 64 + ((lq ^ s) << 4);
    }
    #pragma unroll
    for (int nf = 0; nf < 4; ++nf) {
        int c = wc * 64 + nf * 16 + lr;
        int s = (c + (c >> 2)) & 3;
        boff[nf] = c * 64 + ((lq ^ s) << 4);
    }

    // staging: thread covers region bytes tid*16 (+8192 for shot 1)
    int srow = tid >> 2;                      // row 0..127 (shot0), +128 shot1
    int sx = (srow + (srow >> 2)) & 3;        // s(row) == s(row+128)
    int kxor = (tid & 3) ^ sx;
    const uint16_t* gA0 = A  + (size_t)(row0 + srow) * K + kxor * 8;
    const uint16_t* gB0 = Be + (size_t)srow * K + kxor * 8;
    char* ldsb = (char*)&lds[0];

    auto STAGE = [&](int kind, int tdst, int reg) {
        int kcol = tdst * 64 + (kind >> 1) * 32;
        const uint16_t* g = (kind & 1) ? gB0 : gA0;
        #pragma unroll
        for (int s = 0; s < 2; ++s) {
            __builtin_amdgcn_global_load_lds(
                (const __attribute__((address_space(1))) void*)(g + (size_t)s * 128 * K + kcol),
                (__attribute__((address_space(3))) void*)(ldsb + reg * HT + s * 8192 + tid * 16),
                16, 0, 0);
        }
    };

    f4 acc[8][4] = {};
    int nkt = K >> 6;

    // prologue: stage K-tile 0 (h0..h3 -> regions 0..3)
    STAGE(0, 0, 0); STAGE(1, 0, 1); STAGE(2, 0, 2); STAGE(3, 0, 3);
    asm volatile("s_waitcnt vmcnt(4)" ::: "memory");
    __builtin_amdgcn_s_barrier();

    short8 af[8];
    for (int t2 = 0; t2 < nkt; t2 += 2) {
        bool notlast = (t2 + 2) < nkt;
        #pragma unroll
        for (int ph = 0; ph < 8; ++ph) {
            const int u  = ph >> 2;              // which K-tile of the pair
            const int nh = ph & 1;               // n-half
            const int rdA = u * 4 + (((ph >> 1) & 1) << 1);
            const int rdB = rdA + 1;
            // ds-load register subtile
            short8 bfr[2];
            if (nh == 0) {
                #pragma unroll
                for (int m = 0; m < 8; ++m)
                    af[m] = *(const short8*)(ldsb + rdA * HT + aoff[m]);
            }
            bfr[0] = *(const short8*)(ldsb + rdB * HT + boff[nh*2+0]);
            bfr[1] = *(const short8*)(ldsb + rdB * HT + boff[nh*2+1]);
            // stage half-tile (lead 4 phases): kind ph&3 of K-tile t2+u+1
            if (u == 0 || notlast)
                STAGE(ph & 3, t2 + u + 1, (u ? 0 : 4) + (ph & 3));
            // counted vmcnt once per K-tile pair boundary (odd phases)
            if (nh == 1) {
                if (!notlast && ph == 5)
                    asm volatile("s_waitcnt vmcnt(0)" ::: "memory");
                else
                    asm volatile("s_waitcnt vmcnt(4)" ::: "memory");
            }
            __builtin_amdgcn_s_barrier();
            asm volatile("s_waitcnt lgkmcnt(0)" ::: "memory");
            __builtin_amdgcn_sched_barrier(0);
            __builtin_amdgcn_s_setprio(1);
            #pragma unroll
            for (int m = 0; m < 8; ++m) {
                acc[m][nh*2+0] = __builtin_amdgcn_mfma_f32_16x16x32_bf16(
                    af[m], bfr[0], acc[m][nh*2+0], 0, 0, 0);
                acc[m][nh*2+1] = __builtin_amdgcn_mfma_f32_16x16x32_bf16(
                    af[m], bfr[1], acc[m][nh*2+1], 0, 0, 0);
            }
            __builtin_amdgcn_s_setprio(0);
            __builtin_amdgcn_s_barrier();
        }
    }

    // epilogue: +bias (opt ReLU) -> bf16
    float bv[4];
    #pragma unroll
    for (int nf = 0; nf < 4; ++nf)
        bv[nf] = bias[(size_t)e * N + n0 + wc*64 + nf*16 + lr];
    #pragma unroll
    for (int m = 0; m < 8; ++m) {
        int rb = row0 + wr*128 + m*16 + lq*4;
        #pragma unroll
        for (int nf = 0; nf < 4; ++nf) {
            int c = n0 + wc*64 + nf*16 + lr;
            #pragma unroll
            for (int r = 0; r < 4; ++r) {
                float v = acc[m][nf][r] + bv[nf];
                if (RELU) v = fmaxf(v, 0.f);
                Cc[(size_t)(rb + r) * N + c] = f2bf(v);
            }
        }
    }
}

// ---------------- combine ----------------
__global__ __launch_bounds__(256) void combine_kernel(
    const uint16_t* __restrict__ Y, const int* __restrict__ pair_slot,
    const float* __restrict__ top_p, float* __restrict__ out)
{
    int t = blockIdx.x;
    int s0 = pair_slot[t*2], s1 = pair_slot[t*2+1];
    float p0 = top_p[t*2],  p1 = top_p[t*2+1];
    int i = threadIdx.x * 4;
    us4 a = *(const us4*)(Y + (size_t)s0 * D_DIM + i);
    us4 b = *(const us4*)(Y + (size_t)s1 * D_DIM + i);
    f4 o;
    o[0] = p0 * bf2f(a.x) + p1 * bf2f(b.x);
    o[1] = p0 * bf2f(a.y) + p1 * bf2f(b.y);
    o[2] = p0 * bf2f(a.z) + p1 * bf2f(b.z);
    o[3] = p0 * bf2f(a.w) + p1 * bf2f(b.w);
    *(f4*)(out + (size_t)t * D_DIM + i) = o;
}

extern "C" void kernel_launch(void* const* d_in, const int* in_sizes, int n_in,
                              void* d_out, int out_size, void* d_ws, size_t ws_size,
                              hipStream_t stream)
{
    const float* x  = (const float*)d_in[0];
    const float* gw = (const float*)d_in[1];
    const float* gb = (const float*)d_in[2];
    const float* w1 = (const float*)d_in[3];
    const float* b1 = (const float*)d_in[4];
    const float* w2 = (const float*)d_in[5];
    const float* b2 = (const float*)d_in[6];
    float* out = (float*)d_out;

    char* ws = (char*)d_ws;
    int*   cnt   = (int*)(ws + WS_CNT);
    int*   cur   = (int*)(ws + WS_CUR);
    int*   sbase = (int*)(ws + WS_SBASE);
    int*   tbase = (int*)(ws + WS_TBASE);
    int*   topi  = (int*)(ws + WS_TOPI);
    float* topp  = (float*)(ws + WS_TOPP);
    int*   pslot = (int*)(ws + WS_PSLOT);
    uint16_t* xg = (uint16_t*)(ws + WS_XG);
    uint16_t* H  = (uint16_t*)(ws + WS_H);
    uint16_t* Y  = xg;                       // xg dead after GEMM1 -> reuse for Y
    uint16_t* WT = (uint16_t*)(ws + WS_WT);

    hipMemsetAsync(ws, 0, 64, stream);
    gate_kernel<<<T_TOK / 4, 256, 0, stream>>>(x, gw, gb, topi, topp, cnt);
    bases_kernel<<<1, 64, 0, stream>>>(cnt, sbase, tbase);
    gather_kernel<<<T_TOK * 2, 256, 0, stream>>>(x, topi, cur, sbase, pslot, xg);

    convT_kernel<<<dim3(F_DIM/32, D_DIM/32, NEXP), 256, 0, stream>>>(w1, WT, D_DIM, F_DIM);
    moe_gemm8<true ><<<MT_MAX * (F_DIM / BMX), 512, 0, stream>>>(
        xg, WT, b1, H, tbase, sbase, D_DIM, F_DIM, F_DIM / BMX);
    convT_kernel<<<dim3(D_DIM/32, F_DIM/32, NEXP), 256, 0, stream>>>(w2, WT, F_DIM, D_DIM);
    moe_gemm8<false><<<MT_MAX * (D_DIM / BMX), 512, 0, stream>>>(
        H, WT, b2, Y, tbase, sbase, F_DIM, D_DIM, D_DIM / BMX);

    combine_kernel<<<T_TOK, 256, 0, stream>>>(Y, pslot, topp, out);
}

// Round 4
// 501.805 us; speedup vs baseline: 1.1452x; 1.1452x over previous
//
#include <hip/hip_runtime.h>
#include <stdint.h>

#define T_TOK 4096
#define D_DIM 1024
#define F_DIM 4096
#define NEXP 8
#define BM 128
#define BN 128
#define BK 32
#define CAP 9216      // 8192 pairs + 8*127 worst-case padding, 128-aligned
#define MT_MAX (CAP / BM)

typedef __attribute__((ext_vector_type(8))) short short8;
typedef __attribute__((ext_vector_type(4))) float f4;
typedef __attribute__((ext_vector_type(4))) unsigned short us4;

// ---- ws layout (bytes) — identical to round 2 (proven ws_size >= 161.5 MB) ----
#define WS_CNT     0
#define WS_CUR     32
#define WS_SBASE   64
#define WS_TBASE   96
#define WS_TOPI    256
#define WS_TOPP    (WS_TOPI + T_TOK*2*4)
#define WS_PSLOT   (WS_TOPP + T_TOK*2*4)
#define WS_XG      102400                               // bf16 [CAP][D]
#define WS_H       (WS_XG + (size_t)CAP*D_DIM*2)        // bf16 [CAP][F]
#define WS_Y       (WS_H + (size_t)CAP*F_DIM*2)         // bf16 [CAP][D]
#define WS_WT      (WS_Y + (size_t)CAP*D_DIM*2)         // bf16 [E][N][K] (67 MB, reused)

__device__ __forceinline__ unsigned short f2bf(float f) {
    union { float f; uint32_t u; } c; c.f = f;
    uint32_t r = c.u + 0x7FFFu + ((c.u >> 16) & 1u);
    return (unsigned short)(r >> 16);
}
__device__ __forceinline__ float bf2f(unsigned short h) {
    union { uint32_t u; float f; } c; c.u = ((uint32_t)h) << 16;
    return c.f;
}

// ---------------- gate: fp32 logits, top-2, softmax ----------------
__global__ __launch_bounds__(256) void gate_kernel(
    const float* __restrict__ x, const float* __restrict__ gw,
    const float* __restrict__ gb,
    int* __restrict__ top_idx, float* __restrict__ top_p, int* __restrict__ cnt)
{
    int lane = threadIdx.x & 63;
    int t = blockIdx.x * 4 + (threadIdx.x >> 6);
    const float* xr = x + (size_t)t * D_DIM;
    float acc[8] = {0.f,0.f,0.f,0.f,0.f,0.f,0.f,0.f};
    for (int i = 0; i < 16; ++i) {
        int d = lane + i * 64;
        float xv = xr[d];
        const float* g = gw + d * 8;
        #pragma unroll
        for (int e = 0; e < 8; ++e) acc[e] += xv * g[e];
    }
    #pragma unroll
    for (int e = 0; e < 8; ++e) {
        #pragma unroll
        for (int off = 32; off > 0; off >>= 1)
            acc[e] += __shfl_xor(acc[e], off, 64);
    }
    if (lane == 0) {
        float l[8];
        #pragma unroll
        for (int e = 0; e < 8; ++e) l[e] = acc[e] + gb[e];
        int i0 = 0; float m0 = l[0];
        #pragma unroll
        for (int e = 1; e < 8; ++e) if (l[e] > m0) { m0 = l[e]; i0 = e; }
        int i1 = -1; float m1 = -3.4e38f;
        #pragma unroll
        for (int e = 0; e < 8; ++e) if (e != i0 && l[e] > m1) { m1 = l[e]; i1 = e; }
        float p0 = 1.f / (1.f + expf(m1 - m0));
        top_idx[t*2]   = i0; top_idx[t*2+1] = i1;
        top_p[t*2]     = p0; top_p[t*2+1]   = 1.f - p0;
        atomicAdd(&cnt[i0], 1);
        atomicAdd(&cnt[i1], 1);
    }
}

// ---------------- bases: pad counts to BM, prefix sums ----------------
__global__ void bases_kernel(const int* __restrict__ cnt,
                             int* __restrict__ sbase, int* __restrict__ tbase)
{
    if (threadIdx.x == 0) {
        int b = 0, tb = 0;
        tbase[0] = 0;
        for (int e = 0; e < 8; ++e) {
            sbase[e] = b;
            int mt = (cnt[e] + BM - 1) / BM;
            b  += mt * BM;
            tb += mt;
            tbase[e + 1] = tb;
        }
    }
}

// ---------------- gather ----------------
__global__ __launch_bounds__(256) void gather_kernel(
    const float* __restrict__ x, const int* __restrict__ top_idx,
    int* __restrict__ cursor, const int* __restrict__ sbase,
    int* __restrict__ pair_slot, uint16_t* __restrict__ xg)
{
    __shared__ int s_slot;
    int p = blockIdx.x;
    int t = p >> 1;
    if (threadIdx.x == 0) {
        int e = top_idx[p];
        int slot = sbase[e] + atomicAdd(&cursor[e], 1);
        pair_slot[p] = slot;
        s_slot = slot;
    }
    __syncthreads();
    int slot = s_slot;
    const f4* src = (const f4*)(x + (size_t)t * D_DIM);
    uint16_t* dst = xg + (size_t)slot * D_DIM;
    int i = threadIdx.x;
    f4 v = src[i];
    us4 o;
    o.x = f2bf(v[0]); o.y = f2bf(v[1]); o.z = f2bf(v[2]); o.w = f2bf(v[3]);
    *(us4*)(dst + i * 4) = o;
}

// ---- weight convert+transpose: fp32 [E][K][N] -> bf16 [E][N][K], 64x64 tiles ----
// 512 threads; reads 64Bx2 per thread (coalesced); writes 16B/thread, rows of
// 128B contiguous (old 32x32 version wrote scattered 64B lines).
__global__ __launch_bounds__(512) void convT_kernel(
    const float* __restrict__ W, uint16_t* __restrict__ WT, int K, int N)
{
    __shared__ float ts[64][65];
    int e = blockIdx.z;
    int n0 = blockIdx.x * 64, k0 = blockIdx.y * 64;
    const float* src = W + (size_t)e * K * N + (size_t)k0 * N + n0;
    int t = threadIdx.x;
    int kk = t >> 3, j = t & 7;
    f4 v0 = *(const f4*)(src + (size_t)kk * N + j * 8);
    f4 v1 = *(const f4*)(src + (size_t)kk * N + j * 8 + 4);
    #pragma unroll
    for (int i = 0; i < 4; ++i) ts[j*8 + i][kk] = v0[i];
    #pragma unroll
    for (int i = 0; i < 4; ++i) ts[j*8 + 4 + i][kk] = v1[i];
    __syncthreads();
    int nn = t >> 3;
    short8 o;
    #pragma unroll
    for (int i = 0; i < 8; ++i) o[i] = (short)f2bf(ts[nn][j*8 + i]);
    *(short8*)(WT + (size_t)e * N * K + (size_t)(n0 + nn) * K + k0 + j * 8) = o;
}

// ---------------- grouped GEMM, 2-phase double-buffered ----------------
// A [CAP][K] bf16 x Bt [E][N][K] bf16 -> C [CAP][N] bf16 (+bias, opt ReLU).
// 128x128 tile, BK=32, 4 waves x (4x4 frags of 16x16x32). Both operands via
// global_load_lds w16, linear LDS dest + XOR-pre-swizzled global source
// (reads use same XOR -> 0 conflicts, verified round 2).
// T3-minimum schedule: STAGE(next) issued BEFORE compute(cur); single
// __syncthreads per K-step (its vmcnt(0)+lgkmcnt(0) provides all ordering).
template<bool RELU>
__global__ __launch_bounds__(256, 2) void moe_gemm2(
    const uint16_t* __restrict__ A, const uint16_t* __restrict__ Bt,
    const float* __restrict__ bias, uint16_t* __restrict__ Cc,
    const int* __restrict__ tbase, const int* __restrict__ sbase,
    int K, int N, int NT)
{
    __shared__ uint16_t As[2][BM][BK];   // 2 x 8 KB
    __shared__ uint16_t Bs[2][BN][BK];   // 2 x 8 KB

    // XCD-bijective swizzle (nwg % 8 == 0) + chunk-of-4 m-tiles for L2 reuse
    int nwg = gridDim.x;
    int lin = blockIdx.x;
    int wg = (lin & 7) * (nwg >> 3) + (lin >> 3);
    int q = wg >> 2;
    int nt = q % NT;
    int mt = (wg & 3) + (q / NT) * 4;

    if (mt >= tbase[8]) return;
    int e = 0;
    while (mt >= tbase[e + 1]) ++e;
    int row0 = sbase[e] + (mt - tbase[e]) * BM;
    int n0 = nt * BN;
    const uint16_t* Be = Bt + (size_t)e * N * K + (size_t)n0 * K;

    int tid = threadIdx.x;
    int wid = tid >> 6, lane = tid & 63;
    int wrow = (wid >> 1) * 64, wcol = (wid & 1) * 64;

    f4 acc[4][4] = {};

    // staging geometry (round-2 verified): shot j covers LDS bytes [j*4096, +4096)
    int ovb = tid * 16;
    int rowA[2], koffA[2];
    #pragma unroll
    for (int j = 0; j < 2; ++j) {
        int ov = ovb + j * 4096;
        int row = ov >> 6;
        int cb  = (ov >> 4) & 3;
        rowA[j]  = row;
        koffA[j] = (cb ^ ((row >> 1) & 3)) << 3;   // bf16 elements
    }

    int abyte[4], bbyte[4];
    #pragma unroll
    for (int m = 0; m < 4; ++m) {
        int r = wrow + m * 16 + (lane & 15);
        abyte[m] = r * 64 + ((((lane >> 4) ^ ((r >> 1) & 3))) << 4);
    }
    #pragma unroll
    for (int n = 0; n < 4; ++n) {
        int c = wcol + n * 16 + (lane & 15);
        bbyte[n] = c * 64 + ((((lane >> 4) ^ ((c >> 1) & 3))) << 4);
    }
    const char* As0 = (const char*)&As[0][0][0];
    const char* Bs0 = (const char*)&Bs[0][0][0];

    auto STAGE = [&](int buf, int kt) {
        #pragma unroll
        for (int j = 0; j < 2; ++j) {
            const uint16_t* gpA = A + (size_t)(row0 + rowA[j]) * K + kt + koffA[j];
            __builtin_amdgcn_global_load_lds(
                (const __attribute__((address_space(1))) void*)gpA,
                (__attribute__((address_space(3))) void*)((char*)&As[buf][0][0] + ovb + j * 4096),
                16, 0, 0);
            const uint16_t* gpB = Be + (size_t)rowA[j] * K + kt + koffA[j];
            __builtin_amdgcn_global_load_lds(
                (const __attribute__((address_space(1))) void*)gpB,
                (__attribute__((address_space(3))) void*)((char*)&Bs[buf][0][0] + ovb + j * 4096),
                16, 0, 0);
        }
    };

    STAGE(0, 0);
    __syncthreads();
    int cur = 0;
    for (int kt = BK; kt <= K; kt += BK) {
        if (kt < K) STAGE(cur ^ 1, kt);        // prefetch next tile FIRST
        int cb = cur * 8192;
        short8 af[4], bfr[4];
        #pragma unroll
        for (int m = 0; m < 4; ++m) af[m] = *(const short8*)(As0 + cb + abyte[m]);
        #pragma unroll
        for (int n = 0; n < 4; ++n) bfr[n] = *(const short8*)(Bs0 + cb + bbyte[n]);
        #pragma unroll
        for (int m = 0; m < 4; ++m)
            #pragma unroll
            for (int n = 0; n < 4; ++n)
                acc[m][n] = __builtin_amdgcn_mfma_f32_16x16x32_bf16(
                    af[m], bfr[n], acc[m][n], 0, 0, 0);
        __syncthreads();                        // drains vmcnt+lgkm, guards overwrite
        cur ^= 1;
    }

    #pragma unroll
    for (int n = 0; n < 4; ++n) {
        int c = wcol + n * 16 + (lane & 15);
        float bv = bias[(size_t)e * N + n0 + c];
        #pragma unroll
        for (int m = 0; m < 4; ++m) {
            int rb = wrow + m * 16 + (lane >> 4) * 4;
            #pragma unroll
            for (int r = 0; r < 4; ++r) {
                float v = acc[m][n][r] + bv;
                if (RELU) v = fmaxf(v, 0.f);
                Cc[(size_t)(row0 + rb + r) * N + n0 + c] = f2bf(v);
            }
        }
    }
}

// ---------------- combine ----------------
__global__ __launch_bounds__(256) void combine_kernel(
    const uint16_t* __restrict__ Y, const int* __restrict__ pair_slot,
    const float* __restrict__ top_p, float* __restrict__ out)
{
    int t = blockIdx.x;
    int s0 = pair_slot[t*2], s1 = pair_slot[t*2+1];
    float p0 = top_p[t*2],  p1 = top_p[t*2+1];
    int i = threadIdx.x * 4;
    us4 a = *(const us4*)(Y + (size_t)s0 * D_DIM + i);
    us4 b = *(const us4*)(Y + (size_t)s1 * D_DIM + i);
    f4 o;
    o[0] = p0 * bf2f(a.x) + p1 * bf2f(b.x);
    o[1] = p0 * bf2f(a.y) + p1 * bf2f(b.y);
    o[2] = p0 * bf2f(a.z) + p1 * bf2f(b.z);
    o[3] = p0 * bf2f(a.w) + p1 * bf2f(b.w);
    *(f4*)(out + (size_t)t * D_DIM + i) = o;
}

extern "C" void kernel_launch(void* const* d_in, const int* in_sizes, int n_in,
                              void* d_out, int out_size, void* d_ws, size_t ws_size,
                              hipStream_t stream)
{
    const float* x  = (const float*)d_in[0];
    const float* gw = (const float*)d_in[1];
    const float* gb = (const float*)d_in[2];
    const float* w1 = (const float*)d_in[3];
    const float* b1 = (const float*)d_in[4];
    const float* w2 = (const float*)d_in[5];
    const float* b2 = (const float*)d_in[6];
    float* out = (float*)d_out;

    char* ws = (char*)d_ws;
    int*   cnt   = (int*)(ws + WS_CNT);
    int*   cur   = (int*)(ws + WS_CUR);
    int*   sbase = (int*)(ws + WS_SBASE);
    int*   tbase = (int*)(ws + WS_TBASE);
    int*   topi  = (int*)(ws + WS_TOPI);
    float* topp  = (float*)(ws + WS_TOPP);
    int*   pslot = (int*)(ws + WS_PSLOT);
    uint16_t* xg = (uint16_t*)(ws + WS_XG);
    uint16_t* H  = (uint16_t*)(ws + WS_H);
    uint16_t* Y  = (uint16_t*)(ws + WS_Y);
    uint16_t* WT = (uint16_t*)(ws + WS_WT);

    hipMemsetAsync(ws, 0, 64, stream);
    gate_kernel<<<T_TOK / 4, 256, 0, stream>>>(x, gw, gb, topi, topp, cnt);
    bases_kernel<<<1, 64, 0, stream>>>(cnt, sbase, tbase);
    gather_kernel<<<T_TOK * 2, 256, 0, stream>>>(x, topi, cur, sbase, pslot, xg);

    convT_kernel<<<dim3(F_DIM/64, D_DIM/64, NEXP), 512, 0, stream>>>(w1, WT, D_DIM, F_DIM);
    moe_gemm2<true ><<<MT_MAX * (F_DIM / BN), 256, 0, stream>>>(
        xg, WT, b1, H, tbase, sbase, D_DIM, F_DIM, F_DIM / BN);
    convT_kernel<<<dim3(D_DIM/64, F_DIM/64, NEXP), 512, 0, stream>>>(w2, WT, F_DIM, D_DIM);
    moe_gemm2<false><<<MT_MAX * (D_DIM / BN), 256, 0, stream>>>(
        H, WT, b2, Y, tbase, sbase, F_DIM, D_DIM, D_DIM / BN);

    combine_kernel<<<T_TOK, 256, 0, stream>>>(Y, pslot, topp, out);
}

// Round 5
// 474.737 us; speedup vs baseline: 1.2105x; 1.0570x over previous
//
#include <hip/hip_runtime.h>
#include <stdint.h>

#define T_TOK 4096
#define D_DIM 1024
#define F_DIM 4096
#define NEXP 8
#define BM 128
#define BN 128
#define BK 32
#define CAP 9216      // 8192 pairs + 8*127 worst-case padding, 128-aligned
#define MT_MAX (CAP / BM)

typedef __attribute__((ext_vector_type(8))) short short8;
typedef __attribute__((ext_vector_type(4))) float f4;
typedef __attribute__((ext_vector_type(4))) unsigned short us4;

// ---- ws layout (bytes) — identical to round 2/4 (proven ws_size) ----
#define WS_CNT     0
#define WS_CUR     32
#define WS_SBASE   64
#define WS_TBASE   96
#define WS_TOPI    256
#define WS_TOPP    (WS_TOPI + T_TOK*2*4)
#define WS_PSLOT   (WS_TOPP + T_TOK*2*4)
#define WS_XG      102400                               // bf16 [CAP][D]
#define WS_H       (WS_XG + (size_t)CAP*D_DIM*2)        // bf16 [CAP][F]
#define WS_Y       (WS_H + (size_t)CAP*F_DIM*2)         // bf16 [CAP][D]
#define WS_WT      (WS_Y + (size_t)CAP*D_DIM*2)         // bf16 [E][N][K] (67 MB, reused)

__device__ __forceinline__ unsigned short f2bf(float f) {
    union { float f; uint32_t u; } c; c.f = f;
    uint32_t r = c.u + 0x7FFFu + ((c.u >> 16) & 1u);
    return (unsigned short)(r >> 16);
}
__device__ __forceinline__ float bf2f(unsigned short h) {
    union { uint32_t u; float f; } c; c.u = ((uint32_t)h) << 16;
    return c.f;
}

// ---------------- gate: fp32 logits, top-2, softmax ----------------
__global__ __launch_bounds__(256) void gate_kernel(
    const float* __restrict__ x, const float* __restrict__ gw,
    const float* __restrict__ gb,
    int* __restrict__ top_idx, float* __restrict__ top_p, int* __restrict__ cnt)
{
    int lane = threadIdx.x & 63;
    int t = blockIdx.x * 4 + (threadIdx.x >> 6);
    const float* xr = x + (size_t)t * D_DIM;
    float acc[8] = {0.f,0.f,0.f,0.f,0.f,0.f,0.f,0.f};
    for (int i = 0; i < 16; ++i) {
        int d = lane + i * 64;
        float xv = xr[d];
        const float* g = gw + d * 8;
        #pragma unroll
        for (int e = 0; e < 8; ++e) acc[e] += xv * g[e];
    }
    #pragma unroll
    for (int e = 0; e < 8; ++e) {
        #pragma unroll
        for (int off = 32; off > 0; off >>= 1)
            acc[e] += __shfl_xor(acc[e], off, 64);
    }
    if (lane == 0) {
        float l[8];
        #pragma unroll
        for (int e = 0; e < 8; ++e) l[e] = acc[e] + gb[e];
        int i0 = 0; float m0 = l[0];
        #pragma unroll
        for (int e = 1; e < 8; ++e) if (l[e] > m0) { m0 = l[e]; i0 = e; }
        int i1 = -1; float m1 = -3.4e38f;
        #pragma unroll
        for (int e = 0; e < 8; ++e) if (e != i0 && l[e] > m1) { m1 = l[e]; i1 = e; }
        float p0 = 1.f / (1.f + expf(m1 - m0));
        top_idx[t*2]   = i0; top_idx[t*2+1] = i1;
        top_p[t*2]     = p0; top_p[t*2+1]   = 1.f - p0;
        atomicAdd(&cnt[i0], 1);
        atomicAdd(&cnt[i1], 1);
    }
}

// ---------------- bases: pad counts to BM, prefix sums ----------------
__global__ void bases_kernel(const int* __restrict__ cnt,
                             int* __restrict__ sbase, int* __restrict__ tbase)
{
    if (threadIdx.x == 0) {
        int b = 0, tb = 0;
        tbase[0] = 0;
        for (int e = 0; e < 8; ++e) {
            sbase[e] = b;
            int mt = (cnt[e] + BM - 1) / BM;
            b  += mt * BM;
            tb += mt;
            tbase[e + 1] = tb;
        }
    }
}

// ---------------- gather ----------------
__global__ __launch_bounds__(256) void gather_kernel(
    const float* __restrict__ x, const int* __restrict__ top_idx,
    int* __restrict__ cursor, const int* __restrict__ sbase,
    int* __restrict__ pair_slot, uint16_t* __restrict__ xg)
{
    __shared__ int s_slot;
    int p = blockIdx.x;
    int t = p >> 1;
    if (threadIdx.x == 0) {
        int e = top_idx[p];
        int slot = sbase[e] + atomicAdd(&cursor[e], 1);
        pair_slot[p] = slot;
        s_slot = slot;
    }
    __syncthreads();
    int slot = s_slot;
    const f4* src = (const f4*)(x + (size_t)t * D_DIM);
    uint16_t* dst = xg + (size_t)slot * D_DIM;
    int i = threadIdx.x;
    f4 v = src[i];
    us4 o;
    o.x = f2bf(v[0]); o.y = f2bf(v[1]); o.z = f2bf(v[2]); o.w = f2bf(v[3]);
    *(us4*)(dst + i * 4) = o;
}

// ---- weight convert+transpose: fp32 [E][K][N] -> bf16 [E][N][K], 64x64 tiles ----
__global__ __launch_bounds__(512) void convT_kernel(
    const float* __restrict__ W, uint16_t* __restrict__ WT, int K, int N)
{
    __shared__ float ts[64][65];
    int e = blockIdx.z;
    int n0 = blockIdx.x * 64, k0 = blockIdx.y * 64;
    const float* src = W + (size_t)e * K * N + (size_t)k0 * N + n0;
    int t = threadIdx.x;
    int kk = t >> 3, j = t & 7;
    f4 v0 = *(const f4*)(src + (size_t)kk * N + j * 8);
    f4 v1 = *(const f4*)(src + (size_t)kk * N + j * 8 + 4);
    #pragma unroll
    for (int i = 0; i < 4; ++i) ts[j*8 + i][kk] = v0[i];
    #pragma unroll
    for (int i = 0; i < 4; ++i) ts[j*8 + 4 + i][kk] = v1[i];
    __syncthreads();
    int nn = t >> 3;
    short8 o;
    #pragma unroll
    for (int i = 0; i < 8; ++i) o[i] = (short)f2bf(ts[nn][j*8 + i]);
    *(short8*)(WT + (size_t)e * N * K + (size_t)(n0 + nn) * K + k0 + j * 8) = o;
}

// ---------------- grouped GEMM, 3-buffer ring + counted vmcnt (T4) ----------------
// A [CAP][K] bf16 x Bt [E][N][K] bf16 -> C [CAP][N] bf16 (+bias, opt ReLU).
// 128x128 tile, BK=32, 4 waves x (4x4 frags of 16x16x32). Both operands via
// global_load_lds w16, linear LDS dest + XOR-pre-swizzled global source
// (reads use same XOR -> 0 conflicts, verified rounds 2/4).
// Ring schedule: iter t reads buf[t%3] (landed), stages k[t+2] into buf[(t+2)%3],
// then s_waitcnt vmcnt(4) (k[t+1] landed; k[t+2] stays IN FLIGHT across the
// barrier) + raw s_barrier. No vmcnt(0) drain in the main loop.
template<bool RELU>
__global__ __launch_bounds__(256, 3) void moe_gemm3(
    const uint16_t* __restrict__ A, const uint16_t* __restrict__ Bt,
    const float* __restrict__ bias, uint16_t* __restrict__ Cc,
    const int* __restrict__ tbase, const int* __restrict__ sbase,
    int K, int N, int NT)
{
    __shared__ uint16_t As3[3][BM][BK];   // 3 x 8 KB
    __shared__ uint16_t Bs3[3][BN][BK];   // 3 x 8 KB

    // XCD-bijective swizzle (nwg % 8 == 0) + chunk-of-4 m-tiles for L2 reuse
    int nwg = gridDim.x;
    int lin = blockIdx.x;
    int wg = (lin & 7) * (nwg >> 3) + (lin >> 3);
    int q = wg >> 2;
    int nt = q % NT;
    int mt = (wg & 3) + (q / NT) * 4;

    if (mt >= tbase[8]) return;
    int e = 0;
    while (mt >= tbase[e + 1]) ++e;
    int row0 = sbase[e] + (mt - tbase[e]) * BM;
    int n0 = nt * BN;
    const uint16_t* Be = Bt + (size_t)e * N * K + (size_t)n0 * K;

    int tid = threadIdx.x;
    int wid = tid >> 6, lane = tid & 63;
    int wrow = (wid >> 1) * 64, wcol = (wid & 1) * 64;

    f4 acc[4][4] = {};

    // staging geometry (rounds 2/4 verified): shot j covers LDS bytes [j*4096, +4096)
    int ovb = tid * 16;
    int rowA[2], koffA[2];
    #pragma unroll
    for (int j = 0; j < 2; ++j) {
        int ov = ovb + j * 4096;
        int row = ov >> 6;
        int cb  = (ov >> 4) & 3;
        rowA[j]  = row;
        koffA[j] = (cb ^ ((row >> 1) & 3)) << 3;   // bf16 elements
    }

    int abyte[4], bbyte[4];
    #pragma unroll
    for (int m = 0; m < 4; ++m) {
        int r = wrow + m * 16 + (lane & 15);
        abyte[m] = r * 64 + ((((lane >> 4) ^ ((r >> 1) & 3))) << 4);
    }
    #pragma unroll
    for (int n = 0; n < 4; ++n) {
        int c = wcol + n * 16 + (lane & 15);
        bbyte[n] = c * 64 + ((((lane >> 4) ^ ((c >> 1) & 3))) << 4);
    }
    const char* As0 = (const char*)&As3[0][0][0];
    const char* Bs0 = (const char*)&Bs3[0][0][0];

    auto STAGE = [&](int buf, int kt) {   // 4 global_load_lds per call
        #pragma unroll
        for (int j = 0; j < 2; ++j) {
            const uint16_t* gpA = A + (size_t)(row0 + rowA[j]) * K + kt + koffA[j];
            __builtin_amdgcn_global_load_lds(
                (const __attribute__((address_space(1))) void*)gpA,
                (__attribute__((address_space(3))) void*)((char*)&As3[buf][0][0] + ovb + j * 4096),
                16, 0, 0);
            const uint16_t* gpB = Be + (size_t)rowA[j] * K + kt + koffA[j];
            __builtin_amdgcn_global_load_lds(
                (const __attribute__((address_space(1))) void*)gpB,
                (__attribute__((address_space(3))) void*)((char*)&Bs3[buf][0][0] + ovb + j * 4096),
                16, 0, 0);
        }
    };

    int nkt = K / BK;
    // prologue: k0 -> buf0, k1 -> buf1; wait k0 only (k1 stays in flight)
    STAGE(0, 0);
    STAGE(1, BK);
    asm volatile("s_waitcnt vmcnt(4)" ::: "memory");
    __builtin_amdgcn_s_barrier();

    int buf = 0;
    for (int t = 0; t < nkt; ++t) {
        int cb = buf * 8192;
        short8 af[4], bfr[4];
        #pragma unroll
        for (int m = 0; m < 4; ++m) af[m] = *(const short8*)(As0 + cb + abyte[m]);
        #pragma unroll
        for (int n = 0; n < 4; ++n) bfr[n] = *(const short8*)(Bs0 + cb + bbyte[n]);

        bool stg = (t + 2) < nkt;             // uniform across block
        if (stg) {
            int b2 = buf + 2; if (b2 >= 3) b2 -= 3;
            STAGE(b2, (t + 2) * BK);
        }

        #pragma unroll
        for (int m = 0; m < 4; ++m)
            #pragma unroll
            for (int n = 0; n < 4; ++n)
                acc[m][n] = __builtin_amdgcn_mfma_f32_16x16x32_bf16(
                    af[m], bfr[n], acc[m][n], 0, 0, 0);

        if (stg) asm volatile("s_waitcnt vmcnt(4)" ::: "memory");
        else     asm volatile("s_waitcnt vmcnt(0)" ::: "memory");
        __builtin_amdgcn_s_barrier();
        buf = (buf + 1 == 3) ? 0 : buf + 1;
    }

    #pragma unroll
    for (int n = 0; n < 4; ++n) {
        int c = wcol + n * 16 + (lane & 15);
        float bv = bias[(size_t)e * N + n0 + c];
        #pragma unroll
        for (int m = 0; m < 4; ++m) {
            int rb = wrow + m * 16 + (lane >> 4) * 4;
            #pragma unroll
            for (int r = 0; r < 4; ++r) {
                float v = acc[m][n][r] + bv;
                if (RELU) v = fmaxf(v, 0.f);
                Cc[(size_t)(row0 + rb + r) * N + n0 + c] = f2bf(v);
            }
        }
    }
}

// ---------------- combine ----------------
__global__ __launch_bounds__(256) void combine_kernel(
    const uint16_t* __restrict__ Y, const int* __restrict__ pair_slot,
    const float* __restrict__ top_p, float* __restrict__ out)
{
    int t = blockIdx.x;
    int s0 = pair_slot[t*2], s1 = pair_slot[t*2+1];
    float p0 = top_p[t*2],  p1 = top_p[t*2+1];
    int i = threadIdx.x * 4;
    us4 a = *(const us4*)(Y + (size_t)s0 * D_DIM + i);
    us4 b = *(const us4*)(Y + (size_t)s1 * D_DIM + i);
    f4 o;
    o[0] = p0 * bf2f(a.x) + p1 * bf2f(b.x);
    o[1] = p0 * bf2f(a.y) + p1 * bf2f(b.y);
    o[2] = p0 * bf2f(a.z) + p1 * bf2f(b.z);
    o[3] = p0 * bf2f(a.w) + p1 * bf2f(b.w);
    *(f4*)(out + (size_t)t * D_DIM + i) = o;
}

extern "C" void kernel_launch(void* const* d_in, const int* in_sizes, int n_in,
                              void* d_out, int out_size, void* d_ws, size_t ws_size,
                              hipStream_t stream)
{
    const float* x  = (const float*)d_in[0];
    const float* gw = (const float*)d_in[1];
    const float* gb = (const float*)d_in[2];
    const float* w1 = (const float*)d_in[3];
    const float* b1 = (const float*)d_in[4];
    const float* w2 = (const float*)d_in[5];
    const float* b2 = (const float*)d_in[6];
    float* out = (float*)d_out;

    char* ws = (char*)d_ws;
    int*   cnt   = (int*)(ws + WS_CNT);
    int*   cur   = (int*)(ws + WS_CUR);
    int*   sbase = (int*)(ws + WS_SBASE);
    int*   tbase = (int*)(ws + WS_TBASE);
    int*   topi  = (int*)(ws + WS_TOPI);
    float* topp  = (float*)(ws + WS_TOPP);
    int*   pslot = (int*)(ws + WS_PSLOT);
    uint16_t* xg = (uint16_t*)(ws + WS_XG);
    uint16_t* H  = (uint16_t*)(ws + WS_H);
    uint16_t* Y  = (uint16_t*)(ws + WS_Y);
    uint16_t* WT = (uint16_t*)(ws + WS_WT);

    hipMemsetAsync(ws, 0, 64, stream);
    gate_kernel<<<T_TOK / 4, 256, 0, stream>>>(x, gw, gb, topi, topp, cnt);
    bases_kernel<<<1, 64, 0, stream>>>(cnt, sbase, tbase);
    gather_kernel<<<T_TOK * 2, 256, 0, stream>>>(x, topi, cur, sbase, pslot, xg);

    convT_kernel<<<dim3(F_DIM/64, D_DIM/64, NEXP), 512, 0, stream>>>(w1, WT, D_DIM, F_DIM);
    moe_gemm3<true ><<<MT_MAX * (F_DIM / BN), 256, 0, stream>>>(
        xg, WT, b1, H, tbase, sbase, D_DIM, F_DIM, F_DIM / BN);
    convT_kernel<<<dim3(D_DIM/64, F_DIM/64, NEXP), 512, 0, stream>>>(w2, WT, F_DIM, D_DIM);
    moe_gemm3<false><<<MT_MAX * (D_DIM / BN), 256, 0, stream>>>(
        H, WT, b2, Y, tbase, sbase, F_DIM, D_DIM, D_DIM / BN);

    combine_kernel<<<T_TOK, 256, 0, stream>>>(Y, pslot, topp, out);
}

// Round 6
// 299.096 us; speedup vs baseline: 1.9214x; 1.5872x over previous
//
#include <hip/hip_runtime.h>
#include <stdint.h>

#define T_TOK 4096
#define D_DIM 1024
#define F_DIM 4096
#define NEXP 8
#define BM 128
#define BN 128
#define BK 32
#define CAP 9216      // 8192 pairs + 8*127 worst-case padding, 128-aligned
#define MT_MAX (CAP / BM)

typedef __attribute__((ext_vector_type(8))) short short8;
typedef __attribute__((ext_vector_type(4))) float f4;
typedef __attribute__((ext_vector_type(4))) unsigned short us4;

// ---- ws layout (bytes) — offsets unchanged from rounds 2-5 (proven ws_size) ----
#define WS_SBASE   64
#define WS_TBASE   96
#define WS_TOPI    256
#define WS_TOPP    (WS_TOPI + T_TOK*2*4)
#define WS_PSLOT   (WS_TOPP + T_TOK*2*4)
#define WS_XG      102400                               // bf16 [CAP][D]
#define WS_H       (WS_XG + (size_t)CAP*D_DIM*2)        // bf16 [CAP][F]
#define WS_Y       (WS_H + (size_t)CAP*F_DIM*2)         // bf16 [CAP][D]
#define WS_WT      (WS_Y + (size_t)CAP*D_DIM*2)         // bf16 [E][N][K] (67 MB, reused)

__device__ __forceinline__ unsigned short f2bf(float f) {
    union { float f; uint32_t u; } c; c.f = f;
    uint32_t r = c.u + 0x7FFFu + ((c.u >> 16) & 1u);
    return (unsigned short)(r >> 16);
}
__device__ __forceinline__ float bf2f(unsigned short h) {
    union { uint32_t u; float f; } c; c.u = ((uint32_t)h) << 16;
    return c.f;
}

// ---------------- gate: fp32 logits, top-2, softmax (NO atomics) ----------------
__global__ __launch_bounds__(256) void gate_kernel(
    const float* __restrict__ x, const float* __restrict__ gw,
    const float* __restrict__ gb,
    int* __restrict__ top_idx, float* __restrict__ top_p)
{
    int lane = threadIdx.x & 63;
    int t = blockIdx.x * 4 + (threadIdx.x >> 6);
    const float* xr = x + (size_t)t * D_DIM;
    float acc[8] = {0.f,0.f,0.f,0.f,0.f,0.f,0.f,0.f};
    for (int i = 0; i < 16; ++i) {
        int d = lane + i * 64;
        float xv = xr[d];
        const float* g = gw + d * 8;
        #pragma unroll
        for (int e = 0; e < 8; ++e) acc[e] += xv * g[e];
    }
    #pragma unroll
    for (int e = 0; e < 8; ++e) {
        #pragma unroll
        for (int off = 32; off > 0; off >>= 1)
            acc[e] += __shfl_xor(acc[e], off, 64);
    }
    if (lane == 0) {
        float l[8];
        #pragma unroll
        for (int e = 0; e < 8; ++e) l[e] = acc[e] + gb[e];
        int i0 = 0; float m0 = l[0];
        #pragma unroll
        for (int e = 1; e < 8; ++e) if (l[e] > m0) { m0 = l[e]; i0 = e; }
        int i1 = -1; float m1 = -3.4e38f;
        #pragma unroll
        for (int e = 0; e < 8; ++e) if (e != i0 && l[e] > m1) { m1 = l[e]; i1 = e; }
        float p0 = 1.f / (1.f + expf(m1 - m0));
        top_idx[t*2]   = i0; top_idx[t*2+1] = i1;
        top_p[t*2]     = p0; top_p[t*2+1]   = 1.f - p0;
    }
}

// ---------------- plan: counts + bases + deterministic rank-based slots ----------------
// Single block, 256 threads, 32 pairs/thread. Register histograms (static-indexed),
// per-wave __shfl_up scan per expert, cross-wave combine, then slot assignment.
__global__ __launch_bounds__(256) void plan_kernel(
    const int* __restrict__ top_idx, int* __restrict__ sbase,
    int* __restrict__ tbase, int* __restrict__ pslot)
{
    __shared__ int woff[4][8];
    __shared__ int sb_s[8];
    int t = threadIdx.x, wv = t >> 6, lane = t & 63;
    int base = t * 32;

    int h[8] = {0,0,0,0,0,0,0,0};
    for (int i = 0; i < 32; ++i) {
        int e = top_idx[base + i];
        #pragma unroll
        for (int ee = 0; ee < 8; ++ee) h[ee] += (e == ee) ? 1 : 0;
    }
    int inc[8];
    #pragma unroll
    for (int ee = 0; ee < 8; ++ee) {
        int v = h[ee];
        #pragma unroll
        for (int off = 1; off < 64; off <<= 1) {
            int n = __shfl_up(v, off, 64);
            if (lane >= off) v += n;
        }
        inc[ee] = v;
    }
    if (lane == 63) {
        #pragma unroll
        for (int ee = 0; ee < 8; ++ee) woff[wv][ee] = inc[ee];
    }
    __syncthreads();
    if (t == 0) {
        int cnt[8];
        #pragma unroll
        for (int ee = 0; ee < 8; ++ee) {
            int s = 0;
            #pragma unroll
            for (int w = 0; w < 4; ++w) { int v = woff[w][ee]; woff[w][ee] = s; s += v; }
            cnt[ee] = s;
        }
        int b = 0, tb0 = 0;
        tbase[0] = 0;
        #pragma unroll
        for (int e = 0; e < 8; ++e) {
            sb_s[e] = b; sbase[e] = b;
            int mt = (cnt[e] + BM - 1) / BM;
            b += mt * BM; tb0 += mt;
            tbase[e + 1] = tb0;
        }
    }
    __syncthreads();
    int run[8];
    #pragma unroll
    for (int ee = 0; ee < 8; ++ee)
        run[ee] = sb_s[ee] + woff[wv][ee] + inc[ee] - h[ee];   // exclusive prefix
    for (int i = 0; i < 32; ++i) {
        int e = top_idx[base + i];
        int slot = 0;
        #pragma unroll
        for (int ee = 0; ee < 8; ++ee) slot += (e == ee) ? run[ee] : 0;
        pslot[base + i] = slot;
        #pragma unroll
        for (int ee = 0; ee < 8; ++ee) run[ee] += (e == ee) ? 1 : 0;
    }
}

// ---------------- gather: one block per TOKEN, x row read once, two slot writes ----------------
__global__ __launch_bounds__(256) void gather_kernel(
    const float* __restrict__ x, const int* __restrict__ pslot,
    uint16_t* __restrict__ xg)
{
    int t = blockIdx.x;
    int s0 = pslot[2*t], s1 = pslot[2*t + 1];
    int i = threadIdx.x;
    f4 v = ((const f4*)(x + (size_t)t * D_DIM))[i];
    us4 o;
    o.x = f2bf(v[0]); o.y = f2bf(v[1]); o.z = f2bf(v[2]); o.w = f2bf(v[3]);
    *(us4*)(xg + (size_t)s0 * D_DIM + i * 4) = o;
    *(us4*)(xg + (size_t)s1 * D_DIM + i * 4) = o;
}

// ---- weight convert+transpose: fp32 [E][K][N] -> bf16 [E][N][K], 64x64 tiles ----
__global__ __launch_bounds__(512) void convT_kernel(
    const float* __restrict__ W, uint16_t* __restrict__ WT, int K, int N)
{
    __shared__ float ts[64][65];
    int e = blockIdx.z;
    int n0 = blockIdx.x * 64, k0 = blockIdx.y * 64;
    const float* src = W + (size_t)e * K * N + (size_t)k0 * N + n0;
    int t = threadIdx.x;
    int kk = t >> 3, j = t & 7;
    f4 v0 = *(const f4*)(src + (size_t)kk * N + j * 8);
    f4 v1 = *(const f4*)(src + (size_t)kk * N + j * 8 + 4);
    #pragma unroll
    for (int i = 0; i < 4; ++i) ts[j*8 + i][kk] = v0[i];
    #pragma unroll
    for (int i = 0; i < 4; ++i) ts[j*8 + 4 + i][kk] = v1[i];
    __syncthreads();
    int nn = t >> 3;
    short8 o;
    #pragma unroll
    for (int i = 0; i < 8; ++i) o[i] = (short)f2bf(ts[nn][j*8 + i]);
    *(short8*)(WT + (size_t)e * N * K + (size_t)(n0 + nn) * K + k0 + j * 8) = o;
}

// ---------------- grouped GEMM, 3-buffer ring + counted vmcnt (T4) — unchanged ----------------
template<bool RELU>
__global__ __launch_bounds__(256, 3) void moe_gemm3(
    const uint16_t* __restrict__ A, const uint16_t* __restrict__ Bt,
    const float* __restrict__ bias, uint16_t* __restrict__ Cc,
    const int* __restrict__ tbase, const int* __restrict__ sbase,
    int K, int N, int NT)
{
    __shared__ uint16_t As3[3][BM][BK];
    __shared__ uint16_t Bs3[3][BN][BK];

    int nwg = gridDim.x;
    int lin = blockIdx.x;
    int wg = (lin & 7) * (nwg >> 3) + (lin >> 3);
    int q = wg >> 2;
    int nt = q % NT;
    int mt = (wg & 3) + (q / NT) * 4;

    if (mt >= tbase[8]) return;
    int e = 0;
    while (mt >= tbase[e + 1]) ++e;
    int row0 = sbase[e] + (mt - tbase[e]) * BM;
    int n0 = nt * BN;
    const uint16_t* Be = Bt + (size_t)e * N * K + (size_t)n0 * K;

    int tid = threadIdx.x;
    int wid = tid >> 6, lane = tid & 63;
    int wrow = (wid >> 1) * 64, wcol = (wid & 1) * 64;

    f4 acc[4][4] = {};

    int ovb = tid * 16;
    int rowA[2], koffA[2];
    #pragma unroll
    for (int j = 0; j < 2; ++j) {
        int ov = ovb + j * 4096;
        int row = ov >> 6;
        int cb  = (ov >> 4) & 3;
        rowA[j]  = row;
        koffA[j] = (cb ^ ((row >> 1) & 3)) << 3;
    }

    int abyte[4], bbyte[4];
    #pragma unroll
    for (int m = 0; m < 4; ++m) {
        int r = wrow + m * 16 + (lane & 15);
        abyte[m] = r * 64 + ((((lane >> 4) ^ ((r >> 1) & 3))) << 4);
    }
    #pragma unroll
    for (int n = 0; n < 4; ++n) {
        int c = wcol + n * 16 + (lane & 15);
        bbyte[n] = c * 64 + ((((lane >> 4) ^ ((c >> 1) & 3))) << 4);
    }
    const char* As0 = (const char*)&As3[0][0][0];
    const char* Bs0 = (const char*)&Bs3[0][0][0];

    auto STAGE = [&](int buf, int kt) {
        #pragma unroll
        for (int j = 0; j < 2; ++j) {
            const uint16_t* gpA = A + (size_t)(row0 + rowA[j]) * K + kt + koffA[j];
            __builtin_amdgcn_global_load_lds(
                (const __attribute__((address_space(1))) void*)gpA,
                (__attribute__((address_space(3))) void*)((char*)&As3[buf][0][0] + ovb + j * 4096),
                16, 0, 0);
            const uint16_t* gpB = Be + (size_t)rowA[j] * K + kt + koffA[j];
            __builtin_amdgcn_global_load_lds(
                (const __attribute__((address_space(1))) void*)gpB,
                (__attribute__((address_space(3))) void*)((char*)&Bs3[buf][0][0] + ovb + j * 4096),
                16, 0, 0);
        }
    };

    int nkt = K / BK;
    STAGE(0, 0);
    STAGE(1, BK);
    asm volatile("s_waitcnt vmcnt(4)" ::: "memory");
    __builtin_amdgcn_s_barrier();

    int buf = 0;
    for (int t = 0; t < nkt; ++t) {
        int cb = buf * 8192;
        short8 af[4], bfr[4];
        #pragma unroll
        for (int m = 0; m < 4; ++m) af[m] = *(const short8*)(As0 + cb + abyte[m]);
        #pragma unroll
        for (int n = 0; n < 4; ++n) bfr[n] = *(const short8*)(Bs0 + cb + bbyte[n]);

        bool stg = (t + 2) < nkt;
        if (stg) {
            int b2 = buf + 2; if (b2 >= 3) b2 -= 3;
            STAGE(b2, (t + 2) * BK);
        }

        #pragma unroll
        for (int m = 0; m < 4; ++m)
            #pragma unroll
            for (int n = 0; n < 4; ++n)
                acc[m][n] = __builtin_amdgcn_mfma_f32_16x16x32_bf16(
                    af[m], bfr[n], acc[m][n], 0, 0, 0);

        if (stg) asm volatile("s_waitcnt vmcnt(4)" ::: "memory");
        else     asm volatile("s_waitcnt vmcnt(0)" ::: "memory");
        __builtin_amdgcn_s_barrier();
        buf = (buf + 1 == 3) ? 0 : buf + 1;
    }

    #pragma unroll
    for (int n = 0; n < 4; ++n) {
        int c = wcol + n * 16 + (lane & 15);
        float bv = bias[(size_t)e * N + n0 + c];
        #pragma unroll
        for (int m = 0; m < 4; ++m) {
            int rb = wrow + m * 16 + (lane >> 4) * 4;
            #pragma unroll
            for (int r = 0; r < 4; ++r) {
                float v = acc[m][n][r] + bv;
                if (RELU) v = fmaxf(v, 0.f);
                Cc[(size_t)(row0 + rb + r) * N + n0 + c] = f2bf(v);
            }
        }
    }
}

// ---------------- combine ----------------
__global__ __launch_bounds__(256) void combine_kernel(
    const uint16_t* __restrict__ Y, const int* __restrict__ pair_slot,
    const float* __restrict__ top_p, float* __restrict__ out)
{
    int t = blockIdx.x;
    int s0 = pair_slot[t*2], s1 = pair_slot[t*2+1];
    float p0 = top_p[t*2],  p1 = top_p[t*2+1];
    int i = threadIdx.x * 4;
    us4 a = *(const us4*)(Y + (size_t)s0 * D_DIM + i);
    us4 b = *(const us4*)(Y + (size_t)s1 * D_DIM + i);
    f4 o;
    o[0] = p0 * bf2f(a.x) + p1 * bf2f(b.x);
    o[1] = p0 * bf2f(a.y) + p1 * bf2f(b.y);
    o[2] = p0 * bf2f(a.z) + p1 * bf2f(b.z);
    o[3] = p0 * bf2f(a.w) + p1 * bf2f(b.w);
    *(f4*)(out + (size_t)t * D_DIM + i) = o;
}

extern "C" void kernel_launch(void* const* d_in, const int* in_sizes, int n_in,
                              void* d_out, int out_size, void* d_ws, size_t ws_size,
                              hipStream_t stream)
{
    const float* x  = (const float*)d_in[0];
    const float* gw = (const float*)d_in[1];
    const float* gb = (const float*)d_in[2];
    const float* w1 = (const float*)d_in[3];
    const float* b1 = (const float*)d_in[4];
    const float* w2 = (const float*)d_in[5];
    const float* b2 = (const float*)d_in[6];
    float* out = (float*)d_out;

    char* ws = (char*)d_ws;
    int*   sbase = (int*)(ws + WS_SBASE);
    int*   tbase = (int*)(ws + WS_TBASE);
    int*   topi  = (int*)(ws + WS_TOPI);
    float* topp  = (float*)(ws + WS_TOPP);
    int*   pslot = (int*)(ws + WS_PSLOT);
    uint16_t* xg = (uint16_t*)(ws + WS_XG);
    uint16_t* H  = (uint16_t*)(ws + WS_H);
    uint16_t* Y  = (uint16_t*)(ws + WS_Y);
    uint16_t* WT = (uint16_t*)(ws + WS_WT);

    gate_kernel<<<T_TOK / 4, 256, 0, stream>>>(x, gw, gb, topi, topp);
    plan_kernel<<<1, 256, 0, stream>>>(topi, sbase, tbase, pslot);
    gather_kernel<<<T_TOK, 256, 0, stream>>>(x, pslot, xg);

    convT_kernel<<<dim3(F_DIM/64, D_DIM/64, NEXP), 512, 0, stream>>>(w1, WT, D_DIM, F_DIM);
    moe_gemm3<true ><<<MT_MAX * (F_DIM / BN), 256, 0, stream>>>(
        xg, WT, b1, H, tbase, sbase, D_DIM, F_DIM, F_DIM / BN);
    convT_kernel<<<dim3(D_DIM/64, F_DIM/64, NEXP), 512, 0, stream>>>(w2, WT, F_DIM, D_DIM);
    moe_gemm3<false><<<MT_MAX * (D_DIM / BN), 256, 0, stream>>>(
        H, WT, b2, Y, tbase, sbase, F_DIM, D_DIM, D_DIM / BN);

    combine_kernel<<<T_TOK, 256, 0, stream>>>(Y, pslot, topp, out);
}